// Round 1
// baseline (353.785 us; speedup 1.0000x reference)
//
#include <hip/hip_runtime.h>

// ---- problem constants ----
constexpr int N    = 20000;
constexpr int F    = 4;
constexpr int T    = 12;
constexpr int C    = 256;
constexpr int HIDN = 128;
constexpr int OUTD = 12;
constexpr int ER   = 30000;
constexpr int NFT  = F * T;            // 48 floats per node
constexpr int EDGE_TOT = 5 * ER;       // 150000
constexpr int SCAT_TOT = 5 * ER * NFT; // 7.2M

// workspace layout (floats)
//  deg/dinv : [5*N]           at 0
//  coef     : [5*ER]          at 100000
//  xa       : [N*NFT]         at 250000
//  Mv       : [2*(5*C)]       at 1210000   (per gate: M[4][C] then v[C])
constexpr int WS_DEG  = 0;
constexpr int WS_COEF = 100000;
constexpr int WS_XA   = 250000;
constexpr int WS_MV   = 1210000;

__device__ __forceinline__ void pick_region(
    int r,
    const int* e0, const int* e1, const int* e2, const int* e3, const int* e4,
    const float* a0, const float* a1, const float* a2, const float* a3, const float* a4,
    const int*& ei, const float*& ea) {
  switch (r) {
    case 0: ei = e0; ea = a0; break;
    case 1: ei = e1; ea = a1; break;
    case 2: ei = e2; ea = a2; break;
    case 3: ei = e3; ea = a3; break;
    default: ei = e4; ea = a4; break;
  }
}

// 1) deg[r][dst] += w   (deg pre-zeroed by memset)
__global__ void k_deg(const int* __restrict__ e0, const int* __restrict__ e1,
                      const int* __restrict__ e2, const int* __restrict__ e3,
                      const int* __restrict__ e4,
                      const float* __restrict__ a0, const float* __restrict__ a1,
                      const float* __restrict__ a2, const float* __restrict__ a3,
                      const float* __restrict__ a4,
                      float* __restrict__ deg) {
  int i = blockIdx.x * blockDim.x + threadIdx.x;
  if (i >= EDGE_TOT) return;
  int r = i / ER;
  int e = i - r * ER;
  const int* ei; const float* ea;
  pick_region(r, e0, e1, e2, e3, e4, a0, a1, a2, a3, a4, ei, ea);
  atomicAdd(&deg[r * N + ei[ER + e]], ea[e]);
}

// 2) dinv = rsqrt(deg + 1)  (in place)
__global__ void k_dinv(float* __restrict__ deg) {
  int i = blockIdx.x * blockDim.x + threadIdx.x;
  if (i >= 5 * N) return;
  deg[i] = rsqrtf(deg[i] + 1.0f);
}

// 3) coef[r][e] = dinv[src] * w * dinv[dst]
__global__ void k_coef(const int* __restrict__ e0, const int* __restrict__ e1,
                       const int* __restrict__ e2, const int* __restrict__ e3,
                       const int* __restrict__ e4,
                       const float* __restrict__ a0, const float* __restrict__ a1,
                       const float* __restrict__ a2, const float* __restrict__ a3,
                       const float* __restrict__ a4,
                       const float* __restrict__ dinv, float* __restrict__ coef) {
  int i = blockIdx.x * blockDim.x + threadIdx.x;
  if (i >= EDGE_TOT) return;
  int r = i / ER;
  int e = i - r * ER;
  const int* ei; const float* ea;
  pick_region(r, e0, e1, e2, e3, e4, a0, a1, a2, a3, a4, ei, ea);
  int src = ei[e];
  int dst = ei[ER + e];
  coef[i] = dinv[r * N + src] * ea[e] * dinv[r * N + dst];
}

// 4) xa[n][q] = (sum_r dinv_r[n]^2) * x[n][q]   (initializes xa; no memset needed)
__global__ void k_selfinit(const float* __restrict__ x, const float* __restrict__ dinv,
                           float* __restrict__ xa) {
  int i = blockIdx.x * blockDim.x + threadIdx.x;
  if (i >= N * NFT) return;
  int n = i / NFT;
  float s = 0.0f;
#pragma unroll
  for (int r = 0; r < 5; r++) {
    float d = dinv[r * N + n];
    s += d * d;
  }
  xa[i] = s * x[i];
}

// 5) xa[dst][q] += coef * x[src][q]  over all 5 regions' edges
__global__ void k_scatter(const int* __restrict__ e0, const int* __restrict__ e1,
                          const int* __restrict__ e2, const int* __restrict__ e3,
                          const int* __restrict__ e4,
                          const float* __restrict__ coef, const float* __restrict__ x,
                          float* __restrict__ xa) {
  int i = blockIdx.x * blockDim.x + threadIdx.x;
  if (i >= SCAT_TOT) return;
  int r   = i / (ER * NFT);
  int rem = i - r * (ER * NFT);
  int e   = rem / NFT;
  int q   = rem - e * NFT;
  const int* ei;
  switch (r) {
    case 0: ei = e0; break;
    case 1: ei = e1; break;
    case 2: ei = e2; break;
    case 3: ei = e3; break;
    default: ei = e4; break;
  }
  int src = ei[e];
  int dst = ei[ER + e];
  float cf = coef[r * ER + e];
  atomicAdd(&xa[dst * NFT + q], cf * x[src * NFT + q]);
}

// 6) per gate g (0=z,1=h):  M[f][k] = sum_c Wc[f][c]*Wl[c][k];  v[k] = bl[k] + sum_c bc[c]*Wl[c][k]
__global__ void k_mv(const float* __restrict__ Wc_z, const float* __restrict__ bc_z,
                     const float* __restrict__ Wl_z, const float* __restrict__ bl_z,
                     const float* __restrict__ Wc_h, const float* __restrict__ bc_h,
                     const float* __restrict__ Wl_h, const float* __restrict__ bl_h,
                     float* __restrict__ Mv) {
  int g = blockIdx.x;
  int k = threadIdx.x;
  const float* Wc = g ? Wc_h : Wc_z;
  const float* bc = g ? bc_h : bc_z;
  const float* Wl = g ? Wl_h : Wl_z;
  const float* bl = g ? bl_h : bl_z;
  float m0 = 0.f, m1 = 0.f, m2 = 0.f, m3 = 0.f, v = bl[k];
  for (int c = 0; c < C; c++) {
    float wl = Wl[c * C + k];
    m0 = fmaf(Wc[0 * C + c], wl, m0);
    m1 = fmaf(Wc[1 * C + c], wl, m1);
    m2 = fmaf(Wc[2 * C + c], wl, m2);
    m3 = fmaf(Wc[3 * C + c], wl, m3);
    v  = fmaf(bc[c], wl, v);
  }
  float* o = Mv + g * (5 * C);
  o[0 * C + k] = m0;
  o[1 * C + k] = m1;
  o[2 * C + k] = m2;
  o[3 * C + k] = m3;
  o[4 * C + k] = v;
}

// 7) fused gates + attention pooling:  h[n][c] = sum_t p[t]*(1-sigmoid(az))*tanh(ah)
constexpr int NODES_PB = 64;
__global__ __launch_bounds__(256) void k_gates(const float* __restrict__ xa,
                                               const float* __restrict__ Mv,
                                               const float* __restrict__ att,
                                               float* __restrict__ h_out) {
  __shared__ float xs[NFT];
  int c = threadIdx.x;

  // softmax(attention) -- every thread computes it (broadcast loads, tiny)
  float p[T];
  float amax = -3.0e38f;
#pragma unroll
  for (int t = 0; t < T; t++) { p[t] = att[t]; amax = fmaxf(amax, p[t]); }
  float s = 0.f;
#pragma unroll
  for (int t = 0; t < T; t++) { p[t] = __expf(p[t] - amax); s += p[t]; }
  float inv = 1.0f / s;
#pragma unroll
  for (int t = 0; t < T; t++) p[t] *= inv;

  const float* Mz = Mv;
  const float* Mh = Mv + 5 * C;
  float mz0 = Mz[c], mz1 = Mz[C + c], mz2 = Mz[2 * C + c], mz3 = Mz[3 * C + c];
  float vz  = Mz[4 * C + c];
  float mh0 = Mh[c], mh1 = Mh[C + c], mh2 = Mh[2 * C + c], mh3 = Mh[3 * C + c];
  float vh  = Mh[4 * C + c];

  int nbase = blockIdx.x * NODES_PB;
  for (int nl = 0; nl < NODES_PB; nl++) {
    int n = nbase + nl;                 // uniform across block
    __syncthreads();
    if (c < NFT && n < N) xs[c] = xa[n * NFT + c];
    __syncthreads();
    if (n >= N) continue;               // block-uniform, safe
    float acc = 0.f;
#pragma unroll
    for (int t = 0; t < T; t++) {
      float x0 = xs[0 * T + t], x1 = xs[1 * T + t], x2 = xs[2 * T + t], x3 = xs[3 * T + t];
      float az = fmaf(mz0, x0, fmaf(mz1, x1, fmaf(mz2, x2, fmaf(mz3, x3, vz))));
      float ah = fmaf(mh0, x0, fmaf(mh1, x1, fmaf(mh2, x2, fmaf(mh3, x3, vh))));
      float Z  = 1.0f / (1.0f + __expf(-az));          // sigmoid
      float e2 = __expf(2.0f * ah);
      float th = 1.0f - 2.0f / (e2 + 1.0f);            // tanh, saturates correctly
      acc = fmaf(p[t] * (1.0f - Z), th, acc);
    }
    h_out[n * C + c] = acc;
  }
}

// 8) MLP: y = relu(relu(h) @ W1 + b1) @ W2 + b2.  16 nodes/block (2 groups x 8 acc)
constexpr int MLP_NPB = 16;
__global__ __launch_bounds__(256) void k_mlp(const float* __restrict__ h_in,
                                             const float* __restrict__ W1,
                                             const float* __restrict__ b1,
                                             const float* __restrict__ W2,
                                             const float* __restrict__ b2,
                                             float* __restrict__ y_out) {
  __shared__ float hs[MLP_NPB][C];      // 16 KB
  __shared__ float y1s[MLP_NPB][HIDN];  // 8 KB
  int tid = threadIdx.x;
  int g = tid >> 7;        // group 0/1 -> nodes [g*8, g*8+8)
  int k = tid & 127;       // hidden unit
  int n0 = blockIdx.x * MLP_NPB;

  // stage relu(h) for 16 nodes (coalesced)
  for (int j = tid; j < MLP_NPB * C; j += 256)
    hs[j >> 8][j & 255] = fmaxf(h_in[n0 * C + j], 0.0f);
  __syncthreads();

  float rb1 = b1[k];
  float acc[8];
#pragma unroll
  for (int j = 0; j < 8; j++) acc[j] = rb1;

#pragma unroll 4
  for (int c = 0; c < C; c++) {
    float w = W1[c * HIDN + k];         // streams from L2, coalesced 256B/wave
#pragma unroll
    for (int j = 0; j < 8; j++) acc[j] = fmaf(w, hs[g * 8 + j][c], acc[j]);
  }
#pragma unroll
  for (int j = 0; j < 8; j++) y1s[g * 8 + j][k] = fmaxf(acc[j], 0.0f);
  __syncthreads();

  if (tid < MLP_NPB * OUTD) {           // 192 threads
    int nn = tid / OUTD;
    int jo = tid - nn * OUTD;
    float a = b2[jo];
#pragma unroll 8
    for (int kk = 0; kk < HIDN; kk++) a = fmaf(y1s[nn][kk], W2[kk * OUTD + jo], a);
    y_out[(n0 + nn) * OUTD + jo] = a;
  }
}

extern "C" void kernel_launch(void* const* d_in, const int* in_sizes, int n_in,
                              void* d_out, int out_size, void* d_ws, size_t ws_size,
                              hipStream_t stream) {
  const float* x   = (const float*)d_in[0];
  // d_in[1] = full-graph edge_index: provably unused by the output
  const int* eIA = (const int*)d_in[2];
  const int* eKS = (const int*)d_in[3];
  const int* eKY = (const int*)d_in[4];
  const int* eOH = (const int*)d_in[5];
  const int* eWI = (const int*)d_in[6];
  const float* aIA = (const float*)d_in[7];
  const float* aKS = (const float*)d_in[8];
  const float* aKY = (const float*)d_in[9];
  const float* aOH = (const float*)d_in[10];
  const float* aWI = (const float*)d_in[11];
  const float* Wc_z = (const float*)d_in[12];
  const float* bc_z = (const float*)d_in[13];
  const float* Wl_z = (const float*)d_in[14];
  const float* bl_z = (const float*)d_in[15];
  // r-gate params (16..19) provably cannot influence the output (H=0)
  const float* Wc_h = (const float*)d_in[20];
  const float* bc_h = (const float*)d_in[21];
  const float* Wl_h = (const float*)d_in[22];
  const float* bl_h = (const float*)d_in[23];
  const float* att  = (const float*)d_in[24];
  const float* W1   = (const float*)d_in[25];
  const float* b1   = (const float*)d_in[26];
  const float* W2   = (const float*)d_in[27];
  const float* b2   = (const float*)d_in[28];

  float* ws   = (float*)d_ws;
  float* deg  = ws + WS_DEG;   // 5*N, becomes dinv in place
  float* coef = ws + WS_COEF;  // 5*ER
  float* xa   = ws + WS_XA;    // N*NFT
  float* Mv   = ws + WS_MV;    // 2*5*C

  float* y_out = (float*)d_out;            // [N,12]
  float* h_out = y_out + N * OUTD;         // [N,256]

  // zero degree accumulators (ws is poisoned 0xAA before every call)
  hipMemsetAsync(deg, 0, 5 * N * sizeof(float), stream);

  k_deg<<<(EDGE_TOT + 255) / 256, 256, 0, stream>>>(eIA, eKS, eKY, eOH, eWI,
                                                    aIA, aKS, aKY, aOH, aWI, deg);
  k_dinv<<<(5 * N + 255) / 256, 256, 0, stream>>>(deg);
  k_coef<<<(EDGE_TOT + 255) / 256, 256, 0, stream>>>(eIA, eKS, eKY, eOH, eWI,
                                                     aIA, aKS, aKY, aOH, aWI, deg, coef);
  k_selfinit<<<(N * NFT + 255) / 256, 256, 0, stream>>>(x, deg, xa);
  k_scatter<<<(SCAT_TOT + 255) / 256, 256, 0, stream>>>(eIA, eKS, eKY, eOH, eWI,
                                                        coef, x, xa);
  k_mv<<<2, 256, 0, stream>>>(Wc_z, bc_z, Wl_z, bl_z, Wc_h, bc_h, Wl_h, bl_h, Mv);
  k_gates<<<(N + NODES_PB - 1) / NODES_PB, 256, 0, stream>>>(xa, Mv, att, h_out);
  k_mlp<<<N / MLP_NPB, 256, 0, stream>>>(h_out, W1, b1, W2, b2, y_out);
}

// Round 2
// 269.938 us; speedup vs baseline: 1.3106x; 1.3106x over previous
//
#include <hip/hip_runtime.h>

// ---- problem constants ----
constexpr int N    = 20000;
constexpr int F    = 4;
constexpr int T    = 12;
constexpr int C    = 256;
constexpr int HIDN = 128;
constexpr int OUTD = 12;
constexpr int ER   = 30000;
constexpr int NFT  = F * T;            // 48 floats per node
constexpr int EDGE_TOT = 5 * ER;       // 150000
constexpr int SCAT_TOT = 5 * ER * NFT; // 7.2M

// workspace layout (floats) -- deg and xa contiguous so ONE memset covers both
//  deg  : [5*N]    at 0          (raw degree sums; rsqrt folded into consumers)
//  xa   : [N*NFT]  at 100000     (scatter accumulator, needs zero init)
//  coef : [5*ER]   at 1060000
//  Mv   : [10*C + T] at 1210000  (per gate: M[4][C], v[C]; then softmax probs[T])
constexpr int WS_DEG  = 0;
constexpr int WS_XA   = 100000;
constexpr int WS_COEF = 1060000;
constexpr int WS_MV   = 1210000;

__device__ __forceinline__ void pick_region(
    int r,
    const int* e0, const int* e1, const int* e2, const int* e3, const int* e4,
    const float* a0, const float* a1, const float* a2, const float* a3, const float* a4,
    const int*& ei, const float*& ea) {
  switch (r) {
    case 0: ei = e0; ea = a0; break;
    case 1: ei = e1; ea = a1; break;
    case 2: ei = e2; ea = a2; break;
    case 3: ei = e3; ea = a3; break;
    default: ei = e4; ea = a4; break;
  }
}

// 1) deg[r][dst] += w   (deg pre-zeroed by memset)
__global__ void k_deg(const int* __restrict__ e0, const int* __restrict__ e1,
                      const int* __restrict__ e2, const int* __restrict__ e3,
                      const int* __restrict__ e4,
                      const float* __restrict__ a0, const float* __restrict__ a1,
                      const float* __restrict__ a2, const float* __restrict__ a3,
                      const float* __restrict__ a4,
                      float* __restrict__ deg) {
  int i = blockIdx.x * blockDim.x + threadIdx.x;
  if (i >= EDGE_TOT) return;
  int r = i / ER;
  int e = i - r * ER;
  const int* ei; const float* ea;
  pick_region(r, e0, e1, e2, e3, e4, a0, a1, a2, a3, a4, ei, ea);
  atomicAdd(&deg[r * N + ei[ER + e]], ea[e]);
}

// 2) coef[r][e] = rsqrt(deg[src]+1) * w * rsqrt(deg[dst]+1)
__global__ void k_coef(const int* __restrict__ e0, const int* __restrict__ e1,
                       const int* __restrict__ e2, const int* __restrict__ e3,
                       const int* __restrict__ e4,
                       const float* __restrict__ a0, const float* __restrict__ a1,
                       const float* __restrict__ a2, const float* __restrict__ a3,
                       const float* __restrict__ a4,
                       const float* __restrict__ deg, float* __restrict__ coef) {
  int i = blockIdx.x * blockDim.x + threadIdx.x;
  if (i >= EDGE_TOT) return;
  int r = i / ER;
  int e = i - r * ER;
  const int* ei; const float* ea;
  pick_region(r, e0, e1, e2, e3, e4, a0, a1, a2, a3, a4, ei, ea);
  int src = ei[e];
  int dst = ei[ER + e];
  coef[i] = rsqrtf(deg[r * N + src] + 1.0f) * ea[e] * rsqrtf(deg[r * N + dst] + 1.0f);
}

// 3) xa[dst][q] += coef * x[src][q]  (xa pre-zeroed; self-loop handled in gates)
__global__ void k_scatter(const int* __restrict__ e0, const int* __restrict__ e1,
                          const int* __restrict__ e2, const int* __restrict__ e3,
                          const int* __restrict__ e4,
                          const float* __restrict__ coef, const float* __restrict__ x,
                          float* __restrict__ xa) {
  int i = blockIdx.x * blockDim.x + threadIdx.x;
  if (i >= SCAT_TOT) return;
  int r   = i / (ER * NFT);
  int rem = i - r * (ER * NFT);
  int e   = rem / NFT;
  int q   = rem - e * NFT;
  const int* ei;
  switch (r) {
    case 0: ei = e0; break;
    case 1: ei = e1; break;
    case 2: ei = e2; break;
    case 3: ei = e3; break;
    default: ei = e4; break;
  }
  int src = ei[e];
  int dst = ei[ER + e];
  float cf = coef[r * ER + e];
  atomicAdd(&xa[dst * NFT + q], cf * x[src * NFT + q]);
}

// 4) gate-weight collapse M = Wc @ Wl[:C], v = bc @ Wl[:C] + bl; plus softmax(att)
__global__ void k_mv(const float* __restrict__ Wc_z, const float* __restrict__ bc_z,
                     const float* __restrict__ Wl_z, const float* __restrict__ bl_z,
                     const float* __restrict__ Wc_h, const float* __restrict__ bc_h,
                     const float* __restrict__ Wl_h, const float* __restrict__ bl_h,
                     const float* __restrict__ att, float* __restrict__ Mv) {
  int g = blockIdx.x;
  int k = threadIdx.x;
  const float* Wc = g ? Wc_h : Wc_z;
  const float* bc = g ? bc_h : bc_z;
  const float* Wl = g ? Wl_h : Wl_z;
  const float* bl = g ? bl_h : bl_z;
  float m0 = 0.f, m1 = 0.f, m2 = 0.f, m3 = 0.f, v = bl[k];
  for (int c = 0; c < C; c++) {
    float wl = Wl[c * C + k];
    m0 = fmaf(Wc[0 * C + c], wl, m0);
    m1 = fmaf(Wc[1 * C + c], wl, m1);
    m2 = fmaf(Wc[2 * C + c], wl, m2);
    m3 = fmaf(Wc[3 * C + c], wl, m3);
    v  = fmaf(bc[c], wl, v);
  }
  float* o = Mv + g * (5 * C);
  o[0 * C + k] = m0;
  o[1 * C + k] = m1;
  o[2 * C + k] = m2;
  o[3 * C + k] = m3;
  o[4 * C + k] = v;
  if (g == 0 && k < T) {   // softmax(attention), redundantly per thread (12 threads)
    float amax = -3.0e38f;
    for (int t = 0; t < T; t++) amax = fmaxf(amax, att[t]);
    float s = 0.f;
    for (int t = 0; t < T; t++) s += __expf(att[t] - amax);
    Mv[10 * C + k] = __expf(att[k] - amax) / s;
  }
}

// 5) fused gates + attention pooling + MLP.  16 nodes per block, 1250 blocks.
//    h[n][c] = sum_t p[t]*(1-sigmoid(az))*tanh(ah);  y = relu(relu(h)@W1+b1)@W2+b2
constexpr int GNB = 16;
__global__ __launch_bounds__(256) void k_gates_mlp(
    const float* __restrict__ xa, const float* __restrict__ x,
    const float* __restrict__ deg, const float* __restrict__ Mv,
    const float* __restrict__ W1, const float* __restrict__ b1,
    const float* __restrict__ W2, const float* __restrict__ b2,
    float* __restrict__ y_out, float* __restrict__ h_out) {
  __shared__ float xs[GNB * NFT];     // 3 KB: combined xa + s*x per node
  __shared__ float ss[GNB];           // self-loop coefficient per node
  __shared__ float hs[GNB][C];        // 16 KB: relu(h)
  __shared__ float y1s[GNB][HIDN];    // 8 KB
  int tid = threadIdx.x;
  int n0 = blockIdx.x * GNB;

  // self-loop coef s = sum_r 1/(deg_r+1)  (== sum_r dinv_r^2)
  if (tid < GNB) {
    int n = n0 + tid;
    float s = 0.f;
#pragma unroll
    for (int r = 0; r < 5; r++) s += 1.0f / (deg[r * N + n] + 1.0f);
    ss[tid] = s;
  }
  __syncthreads();
  // stage combined node vectors: xs = xa + s*x   (both contiguous, coalesced)
  for (int j = tid; j < GNB * NFT; j += 256) {
    int nl = j / NFT;
    xs[j] = fmaf(ss[nl], x[n0 * NFT + j], xa[n0 * NFT + j]);
  }

  // per-channel collapsed gate weights (c = tid, coalesced)
  int c = tid;
  const float* Mz = Mv;
  const float* Mh = Mv + 5 * C;
  float mz0 = Mz[c], mz1 = Mz[C + c], mz2 = Mz[2 * C + c], mz3 = Mz[3 * C + c];
  float vz  = Mz[4 * C + c];
  float mh0 = Mh[c], mh1 = Mh[C + c], mh2 = Mh[2 * C + c], mh3 = Mh[3 * C + c];
  float vh  = Mh[4 * C + c];
  float p[T];
#pragma unroll
  for (int t = 0; t < T; t++) p[t] = Mv[10 * C + t];
  __syncthreads();

  // gates + temporal pooling: LDS reads are wave-uniform (broadcast, no conflicts)
  for (int nl = 0; nl < GNB; nl++) {
    const float* xv = &xs[nl * NFT];
    float acc = 0.f;
#pragma unroll
    for (int t = 0; t < T; t++) {
      float x0 = xv[t], x1 = xv[T + t], x2 = xv[2 * T + t], x3 = xv[3 * T + t];
      float az = fmaf(mz0, x0, fmaf(mz1, x1, fmaf(mz2, x2, fmaf(mz3, x3, vz))));
      float ah = fmaf(mh0, x0, fmaf(mh1, x1, fmaf(mh2, x2, fmaf(mh3, x3, vh))));
      float Z  = 1.0f / (1.0f + __expf(-az));          // sigmoid
      float e2 = __expf(2.0f * ah);
      float th = 1.0f - 2.0f / (e2 + 1.0f);            // tanh
      acc = fmaf(p[t] * (1.0f - Z), th, acc);
    }
    h_out[(n0 + nl) * C + c] = acc;     // raw h is a required output
    hs[nl][c] = fmaxf(acc, 0.0f);       // relu(h) for the MLP
  }
  __syncthreads();

  // MLP layer 1: 2 groups x 8 nodes, 128 hidden units per group
  int g = tid >> 7;
  int k = tid & 127;
  float rb1 = b1[k];
  float acc8[8];
#pragma unroll
  for (int j = 0; j < 8; j++) acc8[j] = rb1;
#pragma unroll 4
  for (int cc = 0; cc < C; cc++) {
    float w = W1[cc * HIDN + k];        // coalesced, L1-resident across blocks
#pragma unroll
    for (int j = 0; j < 8; j++) acc8[j] = fmaf(w, hs[g * 8 + j][cc], acc8[j]);
  }
#pragma unroll
  for (int j = 0; j < 8; j++) y1s[g * 8 + j][k] = fmaxf(acc8[j], 0.0f);
  __syncthreads();

  // MLP layer 2: 192 threads, one (node, out) each
  if (tid < GNB * OUTD) {
    int nn = tid / OUTD;
    int jo = tid - nn * OUTD;
    float a = b2[jo];
#pragma unroll 8
    for (int kk = 0; kk < HIDN; kk++) a = fmaf(y1s[nn][kk], W2[kk * OUTD + jo], a);
    y_out[(n0 + nn) * OUTD + jo] = a;
  }
}

extern "C" void kernel_launch(void* const* d_in, const int* in_sizes, int n_in,
                              void* d_out, int out_size, void* d_ws, size_t ws_size,
                              hipStream_t stream) {
  const float* x   = (const float*)d_in[0];
  // d_in[1] = full-graph edge_index: provably unused by the output
  const int* eIA = (const int*)d_in[2];
  const int* eKS = (const int*)d_in[3];
  const int* eKY = (const int*)d_in[4];
  const int* eOH = (const int*)d_in[5];
  const int* eWI = (const int*)d_in[6];
  const float* aIA = (const float*)d_in[7];
  const float* aKS = (const float*)d_in[8];
  const float* aKY = (const float*)d_in[9];
  const float* aOH = (const float*)d_in[10];
  const float* aWI = (const float*)d_in[11];
  const float* Wc_z = (const float*)d_in[12];
  const float* bc_z = (const float*)d_in[13];
  const float* Wl_z = (const float*)d_in[14];
  const float* bl_z = (const float*)d_in[15];
  // r-gate params (16..19) provably cannot influence the output (H=0)
  const float* Wc_h = (const float*)d_in[20];
  const float* bc_h = (const float*)d_in[21];
  const float* Wl_h = (const float*)d_in[22];
  const float* bl_h = (const float*)d_in[23];
  const float* att  = (const float*)d_in[24];
  const float* W1   = (const float*)d_in[25];
  const float* b1   = (const float*)d_in[26];
  const float* W2   = (const float*)d_in[27];
  const float* b2   = (const float*)d_in[28];

  float* ws   = (float*)d_ws;
  float* deg  = ws + WS_DEG;   // 5*N raw degree sums
  float* xa   = ws + WS_XA;    // N*NFT scatter accumulator
  float* coef = ws + WS_COEF;  // 5*ER
  float* Mv   = ws + WS_MV;    // 10*C + T

  float* y_out = (float*)d_out;            // [N,12]
  float* h_out = y_out + N * OUTD;         // [N,256]

  // k_mv depends only on weights -- issue first
  k_mv<<<2, 256, 0, stream>>>(Wc_z, bc_z, Wl_z, bl_z, Wc_h, bc_h, Wl_h, bl_h, att, Mv);

  // one memset covers deg + xa (contiguous)
  hipMemsetAsync(deg, 0, (5 * N + N * NFT) * sizeof(float), stream);

  k_deg<<<(EDGE_TOT + 255) / 256, 256, 0, stream>>>(eIA, eKS, eKY, eOH, eWI,
                                                    aIA, aKS, aKY, aOH, aWI, deg);
  k_coef<<<(EDGE_TOT + 255) / 256, 256, 0, stream>>>(eIA, eKS, eKY, eOH, eWI,
                                                     aIA, aKS, aKY, aOH, aWI, deg, coef);
  k_scatter<<<(SCAT_TOT + 255) / 256, 256, 0, stream>>>(eIA, eKS, eKY, eOH, eWI,
                                                        coef, x, xa);
  k_gates_mlp<<<N / GNB, 256, 0, stream>>>(xa, x, deg, Mv, W1, b1, W2, b2,
                                           y_out, h_out);
}

// Round 3
// 246.581 us; speedup vs baseline: 1.4348x; 1.0947x over previous
//
#include <hip/hip_runtime.h>

// ---- problem constants ----
constexpr int N    = 20000;
constexpr int F    = 4;
constexpr int T    = 12;
constexpr int C    = 256;
constexpr int HIDN = 128;
constexpr int OUTD = 12;
constexpr int ER   = 30000;
constexpr int NFT  = F * T;            // 48 floats per node
constexpr int EDGE_TOT = 5 * ER;       // 150000
constexpr int SCAT_TOT = 5 * ER * NFT; // 7.2M

// workspace layout (floats); deg+xa+Mv contiguous -> ONE memset
constexpr int WS_DEG  = 0;        // [5*N]
constexpr int WS_XA   = 100000;   // [N*NFT]
constexpr int WS_MV   = 1060000;  // [10*C + T] (z-gate M,v NEGATED; h-gate 2x)
constexpr int WS_COEF = 1062576;  // [5*ER]
constexpr int WS_WP   = 1212576;  // 32768 bf16 (16384 floats): W1 B-fragments
constexpr int WS_W2T  = 1228960;  // [OUTD*HIDN] W2 transposed

typedef __attribute__((ext_vector_type(8))) short short8;
typedef __attribute__((ext_vector_type(4))) float floatx4;

__device__ __forceinline__ short f2bf(float f) {   // RNE float->bf16 (no NaN inputs)
  unsigned u = __float_as_uint(f);
  u = u + 0x7fffu + ((u >> 16) & 1u);
  return (short)(u >> 16);
}

__device__ __forceinline__ void pick_region(
    int r,
    const int* e0, const int* e1, const int* e2, const int* e3, const int* e4,
    const float* a0, const float* a1, const float* a2, const float* a3, const float* a4,
    const int*& ei, const float*& ea) {
  switch (r) {
    case 0: ei = e0; ea = a0; break;
    case 1: ei = e1; ea = a1; break;
    case 2: ei = e2; ea = a2; break;
    case 3: ei = e3; ea = a3; break;
    default: ei = e4; ea = a4; break;
  }
}

// 1) deg[r][dst] += w   (deg pre-zeroed by memset)
__global__ void k_deg(const int* __restrict__ e0, const int* __restrict__ e1,
                      const int* __restrict__ e2, const int* __restrict__ e3,
                      const int* __restrict__ e4,
                      const float* __restrict__ a0, const float* __restrict__ a1,
                      const float* __restrict__ a2, const float* __restrict__ a3,
                      const float* __restrict__ a4,
                      float* __restrict__ deg) {
  int i = blockIdx.x * blockDim.x + threadIdx.x;
  if (i >= EDGE_TOT) return;
  int r = i / ER;
  int e = i - r * ER;
  const int* ei; const float* ea;
  pick_region(r, e0, e1, e2, e3, e4, a0, a1, a2, a3, a4, ei, ea);
  atomicAdd(&deg[r * N + ei[ER + e]], ea[e]);
}

// 2) coef[r][e] = rsqrt(deg[src]+1) * w * rsqrt(deg[dst]+1)
__global__ void k_coef(const int* __restrict__ e0, const int* __restrict__ e1,
                       const int* __restrict__ e2, const int* __restrict__ e3,
                       const int* __restrict__ e4,
                       const float* __restrict__ a0, const float* __restrict__ a1,
                       const float* __restrict__ a2, const float* __restrict__ a3,
                       const float* __restrict__ a4,
                       const float* __restrict__ deg, float* __restrict__ coef) {
  int i = blockIdx.x * blockDim.x + threadIdx.x;
  if (i >= EDGE_TOT) return;
  int r = i / ER;
  int e = i - r * ER;
  const int* ei; const float* ea;
  pick_region(r, e0, e1, e2, e3, e4, a0, a1, a2, a3, a4, ei, ea);
  int src = ei[e];
  int dst = ei[ER + e];
  coef[i] = rsqrtf(deg[r * N + src] + 1.0f) * ea[e] * rsqrtf(deg[r * N + dst] + 1.0f);
}

// 3) xa[dst][q] += coef * x[src][q]  (xa pre-zeroed; self-loop folded into gates)
__global__ void k_scatter(const int* __restrict__ e0, const int* __restrict__ e1,
                          const int* __restrict__ e2, const int* __restrict__ e3,
                          const int* __restrict__ e4,
                          const float* __restrict__ coef, const float* __restrict__ x,
                          float* __restrict__ xa) {
  int i = blockIdx.x * blockDim.x + threadIdx.x;
  if (i >= SCAT_TOT) return;
  int r   = i / (ER * NFT);
  int rem = i - r * (ER * NFT);
  int e   = rem / NFT;
  int q   = rem - e * NFT;
  const int* ei;
  switch (r) {
    case 0: ei = e0; break;
    case 1: ei = e1; break;
    case 2: ei = e2; break;
    case 3: ei = e3; break;
    default: ei = e4; break;
  }
  int src = ei[e];
  int dst = ei[ER + e];
  float cf = coef[r * ER + e];
  atomicAdd(&xa[dst * NFT + q], cf * x[src * NFT + q]);
}

// 4) collapsed gate weights, 16 blocks: M = Wc@Wl[:C], v = bc@Wl[:C]+bl.
//    z-gate stored NEGATED (gates use exp(-az)); h-gate stored 2x (exp(2ah)).
//    Mv pre-zeroed by memset; partials accumulated atomically.
__global__ void k_mv(const float* __restrict__ Wc_z, const float* __restrict__ bc_z,
                     const float* __restrict__ Wl_z, const float* __restrict__ bl_z,
                     const float* __restrict__ Wc_h, const float* __restrict__ bc_h,
                     const float* __restrict__ Wl_h, const float* __restrict__ bl_h,
                     const float* __restrict__ att, float* __restrict__ Mv) {
  int g  = blockIdx.x >> 3;
  int ch = blockIdx.x & 7;
  int k  = threadIdx.x;
  const float* Wc = g ? Wc_h : Wc_z;
  const float* bc = g ? bc_h : bc_z;
  const float* Wl = g ? Wl_h : Wl_z;
  const float* bl = g ? bl_h : bl_z;
  float scale = g ? 2.0f : -1.0f;
  float m0 = 0.f, m1 = 0.f, m2 = 0.f, m3 = 0.f;
  float v = (ch == 0) ? bl[k] : 0.0f;
  int c0 = ch * 32;
  for (int c = c0; c < c0 + 32; c++) {
    float wl = Wl[c * C + k];
    m0 = fmaf(Wc[0 * C + c], wl, m0);
    m1 = fmaf(Wc[1 * C + c], wl, m1);
    m2 = fmaf(Wc[2 * C + c], wl, m2);
    m3 = fmaf(Wc[3 * C + c], wl, m3);
    v  = fmaf(bc[c], wl, v);
  }
  float* o = Mv + g * (5 * C);
  atomicAdd(&o[0 * C + k], scale * m0);
  atomicAdd(&o[1 * C + k], scale * m1);
  atomicAdd(&o[2 * C + k], scale * m2);
  atomicAdd(&o[3 * C + k], scale * m3);
  atomicAdd(&o[4 * C + k], scale * v);
  if (blockIdx.x == 0 && k < T) {   // softmax(attention), single writer
    float amax = -3.0e38f;
    for (int t = 0; t < T; t++) amax = fmaxf(amax, att[t]);
    float s = 0.f;
    for (int t = 0; t < T; t++) s += __expf(att[t] - amax);
    Mv[10 * C + k] = __expf(att[k] - amax) / s;
  }
}

// 5) gates + temporal attention pooling. One WAVE per node, lane owns 4 channels.
//    All node data in registers: zero LDS traffic.
__global__ __launch_bounds__(256) void k_gates(
    const float* __restrict__ xa, const float* __restrict__ x,
    const float* __restrict__ deg, const float* __restrict__ Mv,
    float* __restrict__ h_out) {
  int wave = threadIdx.x >> 6, lane = threadIdx.x & 63;
  int n = blockIdx.x * 4 + wave;          // grid 5000 -> n < 20000 always
  int c0 = lane << 2;
  const float* Mz = Mv;                   // negated
  const float* Mh = Mv + 5 * C;           // 2x
  float mz[4][4], mh[4][4], vz[4], vh[4];
#pragma unroll
  for (int f = 0; f < 4; f++) {
    float4 t1 = *(const float4*)(Mz + f * C + c0);
    mz[f][0] = t1.x; mz[f][1] = t1.y; mz[f][2] = t1.z; mz[f][3] = t1.w;
    float4 t2 = *(const float4*)(Mh + f * C + c0);
    mh[f][0] = t2.x; mh[f][1] = t2.y; mh[f][2] = t2.z; mh[f][3] = t2.w;
  }
  {
    float4 t1 = *(const float4*)(Mz + 4 * C + c0);
    vz[0] = t1.x; vz[1] = t1.y; vz[2] = t1.z; vz[3] = t1.w;
    float4 t2 = *(const float4*)(Mh + 4 * C + c0);
    vh[0] = t2.x; vh[1] = t2.y; vh[2] = t2.z; vh[3] = t2.w;
  }
  float p[T];
#pragma unroll
  for (int t = 0; t < T; t++) p[t] = Mv[10 * C + t];

  // self-loop coefficient s = sum_r 1/(deg_r+1)
  float s = 0.f;
#pragma unroll
  for (int r = 0; r < 5; r++) s += 1.0f / (deg[r * N + n] + 1.0f);

  // combined node vector in registers: xv = xa + s*x  (48 floats)
  float xv[NFT];
#pragma unroll
  for (int i = 0; i < 12; i++) {
    float4 va = *(const float4*)(xa + n * NFT + 4 * i);
    float4 vx = *(const float4*)(x + n * NFT + 4 * i);
    xv[4 * i + 0] = fmaf(s, vx.x, va.x);
    xv[4 * i + 1] = fmaf(s, vx.y, va.y);
    xv[4 * i + 2] = fmaf(s, vx.z, va.z);
    xv[4 * i + 3] = fmaf(s, vx.w, va.w);
  }

  float acc[4] = {0.f, 0.f, 0.f, 0.f};
#pragma unroll
  for (int t = 0; t < T; t++) {
    float x0 = xv[t], x1 = xv[T + t], x2 = xv[2 * T + t], x3 = xv[3 * T + t];
#pragma unroll
    for (int j = 0; j < 4; j++) {
      float az = fmaf(mz[0][j], x0, fmaf(mz[1][j], x1, fmaf(mz[2][j], x2, fmaf(mz[3][j], x3, vz[j]))));
      float ah = fmaf(mh[0][j], x0, fmaf(mh[1][j], x1, fmaf(mh[2][j], x2, fmaf(mh[3][j], x3, vh[j]))));
      float e1 = __expf(az);                        // exp(-az_true)
      float e2 = __expf(ah);                        // exp(2*ah_true)
      float w  = __builtin_amdgcn_rcpf(1.0f + e1);  // 1-Z = e1*w
      float u  = __builtin_amdgcn_rcpf(1.0f + e2);
      float th = fmaf(-2.0f, u, 1.0f);              // tanh
      acc[j] = fmaf(p[t] * (e1 * w), th, acc[j]);
    }
  }
  float4 o = {acc[0], acc[1], acc[2], acc[3]};
  *(float4*)(h_out + n * C + c0) = o;
}

// 6) prep: W1 -> bf16 B-fragment layout Wp[ktile][chunk][lane][j]; W2 -> W2t[o][k]
__global__ void k_prep(const float* __restrict__ W1, const float* __restrict__ W2,
                       short* __restrict__ Wp, float* __restrict__ W2t) {
  int idx = blockIdx.x * 256 + threadIdx.x;
  if (idx < 32768) {
    int j    = idx & 7;
    int lane = (idx >> 3) & 63;
    int ch   = (idx >> 9) & 7;
    int kt   = idx >> 12;
    int cin  = ch * 32 + (lane >> 4) * 8 + j;   // K index
    int kout = kt * 16 + (lane & 15);           // N index
    Wp[idx] = f2bf(W1[cin * HIDN + kout]);
  } else if (idx < 32768 + OUTD * HIDN) {
    int r = idx - 32768;
    int o = r >> 7, k = r & 127;
    W2t[r] = W2[k * OUTD + o];
  }
}

// 7) MLP via bf16 MFMA: wave computes y1[16 nodes][128 k] in 64 MFMAs, then
//    bias+relu -> padded LDS -> tiny layer-2 dots.
__global__ __launch_bounds__(256) void k_mlp(
    const float* __restrict__ h_in, const short* __restrict__ Wp,
    const float* __restrict__ b1, const float* __restrict__ W2t,
    const float* __restrict__ b2, float* __restrict__ y_out) {
  __shared__ float y1s[4][16][132];   // pad 128->132: quad-stride bank offset 16
  int tid = threadIdx.x;
  int wave = tid >> 6, lane = tid & 63;
  int quad = lane >> 4, col = lane & 15;
  int n0 = blockIdx.x * 64 + wave * 16;
  int nA = n0 + col;                  // A-fragment row (m = lane&15)
  if (nA > N - 1) nA = N - 1;         // clamp for tail block
  const float* hrow = h_in + nA * C;

  floatx4 acc[8];
#pragma unroll
  for (int kt = 0; kt < 8; kt++) acc[kt] = {0.f, 0.f, 0.f, 0.f};

#pragma unroll
  for (int ch = 0; ch < 8; ch++) {
    // A: relu(h) -> bf16, elements k = ch*32 + quad*8 + j
    float4 ha = *(const float4*)(hrow + ch * 32 + quad * 8);
    float4 hb = *(const float4*)(hrow + ch * 32 + quad * 8 + 4);
    short8 a;
    a[0] = f2bf(fmaxf(ha.x, 0.f)); a[1] = f2bf(fmaxf(ha.y, 0.f));
    a[2] = f2bf(fmaxf(ha.z, 0.f)); a[3] = f2bf(fmaxf(ha.w, 0.f));
    a[4] = f2bf(fmaxf(hb.x, 0.f)); a[5] = f2bf(fmaxf(hb.y, 0.f));
    a[6] = f2bf(fmaxf(hb.z, 0.f)); a[7] = f2bf(fmaxf(hb.w, 0.f));
#pragma unroll
    for (int kt = 0; kt < 8; kt++) {
      short8 b = ((const short8*)Wp)[(kt * 8 + ch) * 64 + lane];
      acc[kt] = __builtin_amdgcn_mfma_f32_16x16x32_bf16(a, b, acc[kt], 0, 0, 0);
    }
  }
  // bias + relu, stash in LDS.  D layout: row = quad*4+reg, col = lane&15
#pragma unroll
  for (int kt = 0; kt < 8; kt++) {
    float bias = b1[kt * 16 + col];
#pragma unroll
    for (int r = 0; r < 4; r++) {
      y1s[wave][quad * 4 + r][kt * 16 + col] = fmaxf(acc[kt][r] + bias, 0.f);
    }
  }
  __syncthreads();

  // layer 2: 64 nodes x 12 outputs = 768 dots of length 128
#pragma unroll
  for (int rep = 0; rep < 3; rep++) {
    int idx = rep * 256 + tid;
    int nl = idx / 12, o = idx - nl * 12;
    int node = blockIdx.x * 64 + nl;
    float sacc = b2[o];
    const float* yr = &y1s[nl >> 4][nl & 15][0];
    const float* wr = W2t + o * HIDN;
#pragma unroll 8
    for (int k4 = 0; k4 < 32; k4++) {
      float4 yv = *(const float4*)(yr + 4 * k4);
      float4 wv = *(const float4*)(wr + 4 * k4);
      sacc = fmaf(yv.x, wv.x, fmaf(yv.y, wv.y, fmaf(yv.z, wv.z, fmaf(yv.w, wv.w, sacc))));
    }
    if (node < N) y_out[node * OUTD + o] = sacc;
  }
}

extern "C" void kernel_launch(void* const* d_in, const int* in_sizes, int n_in,
                              void* d_out, int out_size, void* d_ws, size_t ws_size,
                              hipStream_t stream) {
  const float* x   = (const float*)d_in[0];
  // d_in[1] = full-graph edge_index: provably unused by the output
  const int* eIA = (const int*)d_in[2];
  const int* eKS = (const int*)d_in[3];
  const int* eKY = (const int*)d_in[4];
  const int* eOH = (const int*)d_in[5];
  const int* eWI = (const int*)d_in[6];
  const float* aIA = (const float*)d_in[7];
  const float* aKS = (const float*)d_in[8];
  const float* aKY = (const float*)d_in[9];
  const float* aOH = (const float*)d_in[10];
  const float* aWI = (const float*)d_in[11];
  const float* Wc_z = (const float*)d_in[12];
  const float* bc_z = (const float*)d_in[13];
  const float* Wl_z = (const float*)d_in[14];
  const float* bl_z = (const float*)d_in[15];
  // r-gate params (16..19) provably cannot influence the output (H=0)
  const float* Wc_h = (const float*)d_in[20];
  const float* bc_h = (const float*)d_in[21];
  const float* Wl_h = (const float*)d_in[22];
  const float* bl_h = (const float*)d_in[23];
  const float* att  = (const float*)d_in[24];
  const float* W1   = (const float*)d_in[25];
  const float* b1   = (const float*)d_in[26];
  const float* W2   = (const float*)d_in[27];
  const float* b2   = (const float*)d_in[28];

  float* ws   = (float*)d_ws;
  float* deg  = ws + WS_DEG;
  float* xa   = ws + WS_XA;
  float* Mv   = ws + WS_MV;
  float* coef = ws + WS_COEF;
  short* Wp   = (short*)(ws + WS_WP);
  float* W2t  = ws + WS_W2T;

  float* y_out = (float*)d_out;            // [N,12]
  float* h_out = y_out + N * OUTD;         // [N,256]

  // one memset covers deg + xa + Mv (contiguous)
  hipMemsetAsync(deg, 0, WS_COEF * sizeof(float), stream);

  k_mv<<<16, 256, 0, stream>>>(Wc_z, bc_z, Wl_z, bl_z, Wc_h, bc_h, Wl_h, bl_h, att, Mv);
  k_deg<<<(EDGE_TOT + 255) / 256, 256, 0, stream>>>(eIA, eKS, eKY, eOH, eWI,
                                                    aIA, aKS, aKY, aOH, aWI, deg);
  k_coef<<<(EDGE_TOT + 255) / 256, 256, 0, stream>>>(eIA, eKS, eKY, eOH, eWI,
                                                     aIA, aKS, aKY, aOH, aWI, deg, coef);
  k_scatter<<<(SCAT_TOT + 255) / 256, 256, 0, stream>>>(eIA, eKS, eKY, eOH, eWI,
                                                        coef, x, xa);
  k_prep<<<134, 256, 0, stream>>>(W1, W2, Wp, W2t);
  k_gates<<<N / 4, 256, 0, stream>>>(xa, x, deg, Mv, h_out);
  k_mlp<<<(N + 63) / 64, 256, 0, stream>>>(h_out, Wp, b1, W2t, b2, y_out);
}